// Round 3
// baseline (458.332 us; speedup 1.0000x reference)
//
#include <hip/hip_runtime.h>
#include <math.h>

typedef unsigned short u16;
typedef __attribute__((ext_vector_type(8))) short short8;
typedef __attribute__((ext_vector_type(4))) short short4v;
typedef __attribute__((ext_vector_type(4))) float floatx4;

#define BB 4
#define NN 1024
#define CC 512
#define HH 8
#define INNERD 512
#define BHCNT 32
#define MTOK 4096

// ---- workspace layout (bytes) ----
constexpr size_t OFF_XB  = 0;                          // bf16 [4096][512]   = 4194304
constexpr size_t OFF_WQB = 4194304;                    // bf16 [1536][512]   = 1572864
constexpr size_t OFF_WPB = 5767168;                    // bf16 [512][512]    = 524288
constexpr size_t OFF_WEB = 6291456;                    // bf16 [64][64]      = 8192
constexpr size_t OFF_WSB = 6299648;                    // bf16 [64][64]      = 8192
constexpr size_t OFF_WHB = 6307840;                    // bf16 [32][64]      = 4096
constexpr size_t OFF_QKV = 6311936;                    // bf16 [3][B][H][N][64] = 12582912
constexpr size_t OFF_EQ  = 18894848;                   // bf16 [BH][N][64]   = 4194304
constexpr size_t OFF_EK  = 23089152;
constexpr size_t OFF_SQ  = 27283456;
constexpr size_t OFF_SK  = 31477760;
constexpr size_t OFF_HQ  = 35672064;                   // bf16 [BH][N][32]   = 2097152
constexpr size_t OFF_HK  = 37769216;
constexpr size_t OFF_VT  = 39866368;                   // bf16 [BH][64][N]   = 4194304
constexpr size_t OFF_EQN = 44060672;                   // fp32 [BH][N]       = 131072
constexpr size_t OFF_EKN = 44191744;
constexpr size_t OFF_HQN = 44322816;
constexpr size_t OFF_HKN = 44453888;
constexpr size_t OFF_AO  = 44584960;                   // bf16 [B][N][512]   = 4194304

__device__ __forceinline__ short f2bf(float f) {
    unsigned u = __float_as_uint(f);
    unsigned r = u + 0x7fffu + ((u >> 16) & 1u);
    return (short)(r >> 16);
}
__device__ __forceinline__ floatx4 mfma16(short8 a, short8 b, floatx4 c) {
    return __builtin_amdgcn_mfma_f32_16x16x32_bf16(a, b, c, 0, 0, 0);
}
__device__ __forceinline__ float softplusf(float x) { return log1pf(expf(x)); }
__device__ __forceinline__ float qsum16(float v) {
    v += __shfl_xor(v, 1); v += __shfl_xor(v, 2);
    v += __shfl_xor(v, 4); v += __shfl_xor(v, 8);
    return v;
}
__device__ __forceinline__ float qmax16(float v) {
    v = fmaxf(v, __shfl_xor(v, 1)); v = fmaxf(v, __shfl_xor(v, 2));
    v = fmaxf(v, __shfl_xor(v, 4)); v = fmaxf(v, __shfl_xor(v, 8));
    return v;
}

// ============================================================================
// K0: fp32 -> bf16 conversion of x / w_qkv / w_proj / w_e / w_s / w_h.
// ============================================================================
__global__ __launch_bounds__(256) void k0_cvt(
    const float* __restrict__ x, const float* __restrict__ wq,
    const float* __restrict__ wp, const float* __restrict__ we,
    const float* __restrict__ wsp, const float* __restrict__ whp,
    u16* __restrict__ xb, u16* __restrict__ wqb, u16* __restrict__ wpb,
    u16* __restrict__ web, u16* __restrict__ wsb, u16* __restrict__ whb) {
    const size_t i = ((size_t)blockIdx.x * 256 + threadIdx.x) * 4;
    const float* s; u16* d; size_t off;
    if (i < 2097152)      { s = x;   d = xb;  off = i; }
    else if (i < 2883584) { s = wq;  d = wqb; off = i - 2097152; }
    else if (i < 3145728) { s = wp;  d = wpb; off = i - 2883584; }
    else if (i < 3149824) { s = we;  d = web; off = i - 3145728; }
    else if (i < 3153920) { s = wsp; d = wsb; off = i - 3149824; }
    else                  { s = whp; d = whb; off = i - 3153920; }
    const float4 v = *(const float4*)(s + off);
    short4v o;
    o[0] = f2bf(v.x); o[1] = f2bf(v.y); o[2] = f2bf(v.z); o[3] = f2bf(v.w);
    *(short4v*)(d + off) = o;
}

// ============================================================================
// K1: qkv = x @ w_qkv^T.  M=4096, O=1536, K=512. bf16 out as qkv[s][b][h][n][d].
// ============================================================================
__global__ __launch_bounds__(256) void k1_qkv(const u16* __restrict__ x,
                                              const u16* __restrict__ wqkv,
                                              u16* __restrict__ qkv) {
    const int tm = blockIdx.x * 64;
    const int o0 = blockIdx.y * 64;
    const int lane = threadIdx.x & 63, w = threadIdx.x >> 6;
    const int l15 = lane & 15, quad = lane >> 4;
    const int arow = tm + w * 16 + l15;

    floatx4 acc[4];
    #pragma unroll
    for (int s = 0; s < 4; ++s) acc[s] = (floatx4){0.f, 0.f, 0.f, 0.f};

    for (int kc = 0; kc < CC / 32; ++kc) {
        const int k0 = kc * 32 + quad * 8;
        short8 a = *(const short8*)(x + (size_t)arow * CC + k0);
        #pragma unroll
        for (int s = 0; s < 4; ++s) {
            short8 b = *(const short8*)(wqkv + (size_t)(o0 + s * 16 + l15) * CC + k0);
            acc[s] = mfma16(a, b, acc[s]);
        }
    }
    #pragma unroll
    for (int s = 0; s < 4; ++s) {
        const int o = o0 + s * 16 + l15;
        const int sq_i = o >> 9, rem = o & 511;
        const int h = rem >> 6, d = rem & 63;
        #pragma unroll
        for (int r = 0; r < 4; ++r) {
            const int tok = tm + w * 16 + quad * 4 + r;
            const int bb = tok >> 10, n = tok & (NN - 1);
            qkv[((((size_t)sq_i * BB + bb) * HH + h) * NN + n) * 64 + d] = (u16)f2bf(acc[s][r]);
        }
    }
}

// ============================================================================
// K2: per-token embeddings (MFMA, K=64) + norms + V transpose.
// ============================================================================
__global__ __launch_bounds__(256) void k2_embed(
    const u16* __restrict__ qkv,
    const u16* __restrict__ we, const float* __restrict__ be,
    const u16* __restrict__ wsp, const float* __restrict__ bsp,
    const u16* __restrict__ whp, const float* __restrict__ bhp,
    u16* __restrict__ eq, u16* __restrict__ ek,
    u16* __restrict__ sq, u16* __restrict__ sk,
    u16* __restrict__ hq, u16* __restrict__ hk,
    float* __restrict__ eqn, float* __restrict__ ekn,
    float* __restrict__ hqn, float* __restrict__ hkn,
    u16* __restrict__ vt) {
    const int bh = blockIdx.x, n0 = blockIdx.y * 64;
    const int b = bh >> 3, h = bh & 7;
    const int tid = threadIdx.x, lane = tid & 63, w = tid >> 6;
    const int l15 = lane & 15, quad = lane >> 4;

    for (int src = 0; src < 2; ++src) {
        const u16* qbase = qkv + (((size_t)src * BB + b) * HH + h) * NN * 64;
        const int tokA = n0 + w * 16 + l15;
        short8 afr[2];
        #pragma unroll
        for (int c = 0; c < 2; ++c)
            afr[c] = *(const short8*)(qbase + (size_t)tokA * 64 + c * 32 + quad * 8);

        floatx4 ce[4], cs[4], ch[2];
        #pragma unroll
        for (int i = 0; i < 4; ++i) { ce[i] = (floatx4){0.f,0.f,0.f,0.f}; cs[i] = (floatx4){0.f,0.f,0.f,0.f}; }
        #pragma unroll
        for (int i = 0; i < 2; ++i) ch[i] = (floatx4){0.f,0.f,0.f,0.f};

        #pragma unroll
        for (int c = 0; c < 2; ++c) {
            const int k0 = c * 32 + quad * 8;
            #pragma unroll
            for (int i = 0; i < 4; ++i) {
                short8 bf = *(const short8*)(we + (size_t)(i * 16 + l15) * 64 + k0);
                ce[i] = mfma16(afr[c], bf, ce[i]);
            }
            #pragma unroll
            for (int i = 0; i < 4; ++i) {
                short8 bf = *(const short8*)(wsp + (size_t)(i * 16 + l15) * 64 + k0);
                cs[i] = mfma16(afr[c], bf, cs[i]);
            }
            #pragma unroll
            for (int i = 0; i < 2; ++i) {
                short8 bf = *(const short8*)(whp + (size_t)(i * 16 + l15) * 64 + k0);
                ch[i] = mfma16(afr[c], bf, ch[i]);
            }
        }
        u16* edst = src ? ek : eq;
        u16* sdst = src ? sk : sq;
        u16* hdst = src ? hk : hq;
        float* endst = src ? ekn : eqn;
        float* hndst = src ? hkn : hqn;

        // ---- Euclid: bias, round, store, |.|^2 of rounded ----
        float epart[4] = {0.f, 0.f, 0.f, 0.f};
        #pragma unroll
        for (int i = 0; i < 4; ++i) {
            const float bias = be[i * 16 + l15];
            #pragma unroll
            for (int r = 0; r < 4; ++r) {
                const float v = ce[i][r] + bias;
                const short vb = f2bf(v);
                const float vr = __uint_as_float(((unsigned)(u16)vb) << 16);
                epart[r] += vr * vr;
                const int tok = n0 + w * 16 + quad * 4 + r;
                edst[((size_t)bh * NN + tok) * 64 + i * 16 + l15] = (u16)vb;
            }
        }
        #pragma unroll
        for (int r = 0; r < 4; ++r) {
            const float s = qsum16(epart[r]);
            if (l15 == 0) endst[(size_t)bh * NN + n0 + w * 16 + quad * 4 + r] = s;
        }
        // ---- spherical: bias, fp32-normalize, round, store ----
        float sv[4][4], sn2[4] = {0.f, 0.f, 0.f, 0.f};
        #pragma unroll
        for (int i = 0; i < 4; ++i) {
            const float bias = bsp[i * 16 + l15];
            #pragma unroll
            for (int r = 0; r < 4; ++r) {
                const float v = cs[i][r] + bias;
                sv[i][r] = v;
                sn2[r] += v * v;
            }
        }
        float inv[4];
        #pragma unroll
        for (int r = 0; r < 4; ++r) {
            const float t = qsum16(sn2[r]);
            inv[r] = 1.0f / fmaxf(sqrtf(t), 1e-12f);
        }
        #pragma unroll
        for (int i = 0; i < 4; ++i) {
            #pragma unroll
            for (int r = 0; r < 4; ++r) {
                const int tok = n0 + w * 16 + quad * 4 + r;
                sdst[((size_t)bh * NN + tok) * 64 + i * 16 + l15] = (u16)f2bf(sv[i][r] * inv[r]);
            }
        }
        // ---- hyperbolic: tanh, round, store, |.|^2 of rounded ----
        float hpart[4] = {0.f, 0.f, 0.f, 0.f};
        #pragma unroll
        for (int i = 0; i < 2; ++i) {
            const float bias = bhp[i * 16 + l15];
            #pragma unroll
            for (int r = 0; r < 4; ++r) {
                const float v = tanhf(ch[i][r] + bias);
                const short vb = f2bf(v);
                const float vr = __uint_as_float(((unsigned)(u16)vb) << 16);
                hpart[r] += vr * vr;
                const int tok = n0 + w * 16 + quad * 4 + r;
                hdst[((size_t)bh * NN + tok) * 32 + i * 16 + l15] = (u16)vb;
            }
        }
        #pragma unroll
        for (int r = 0; r < 4; ++r) {
            const float s = qsum16(hpart[r]);
            if (l15 == 0) hndst[(size_t)bh * NN + n0 + w * 16 + quad * 4 + r] = s;
        }
    }

    // ---- V transpose 64x64 tile -> vt[bh][d][n] bf16 ----
    __shared__ u16 tile[64][72];
    {
        const u16* vbase = qkv + (((size_t)2 * BB + b) * HH + h) * NN * 64;
        const int row = tid >> 2, c0 = (tid & 3) * 16;
        const u16* p = vbase + (size_t)(n0 + row) * 64 + c0;
        *(short8*)(&tile[row][c0]) = *(const short8*)p;
        *(short8*)(&tile[row][c0 + 8]) = *(const short8*)(p + 8);
    }
    __syncthreads();
    {
        const int d = tid >> 2, nn0 = (tid & 3) * 16;
        short8 o1, o2;
        #pragma unroll
        for (int j = 0; j < 8; ++j) o1[j] = (short)tile[nn0 + j][d];
        #pragma unroll
        for (int j = 0; j < 8; ++j) o2[j] = (short)tile[nn0 + 8 + j][d];
        u16* dst = vt + ((size_t)bh * 64 + d) * NN + n0 + nn0;
        *(short8*)dst = o1;
        *(short8*)(dst + 8) = o2;
    }
}

// ============================================================================
// K3: fused distance-attention. grid (BH, N/64), 256 thr, wave = 16 q-rows.
// ============================================================================
__global__ __launch_bounds__(256) void k3_attn(
    const u16* __restrict__ eq, const u16* __restrict__ ek,
    const u16* __restrict__ sq, const u16* __restrict__ sk,
    const u16* __restrict__ hq, const u16* __restrict__ hk,
    const float* __restrict__ eqn, const float* __restrict__ ekn,
    const float* __restrict__ hqn, const float* __restrict__ hkn,
    const u16* __restrict__ vt, u16* __restrict__ ao,
    const float* __restrict__ pA, const float* __restrict__ pB,
    const float* __restrict__ pG, const float* __restrict__ pT) {
    __shared__ u16 plds[4][16][40];   // pad 32->40 shorts

    const int bh = blockIdx.x, q0b = blockIdx.y * 64;
    const int b = bh >> 3, h = bh & 7;
    const int tid = threadIdx.x, lane = tid & 63, w = tid >> 6;
    const int l15 = lane & 15, quad = lane >> 4;
    const int q0 = q0b + w * 16;

    const float spA = softplusf(pA[0]);
    const float spB = softplusf(pB[0]);
    const float spG = softplusf(pG[0]);
    const float invT = 1.0f / softplusf(pT[0]);

    // A-operand fragments for this wave's 16 q-rows
    short8 Ea[2], Sa[2], Ha;
    #pragma unroll
    for (int c = 0; c < 2; ++c) {
        Ea[c] = *(const short8*)(eq + ((size_t)bh * NN + q0 + l15) * 64 + c * 32 + quad * 8);
        Sa[c] = *(const short8*)(sq + ((size_t)bh * NN + q0 + l15) * 64 + c * 32 + quad * 8);
    }
    Ha = *(const short8*)(hq + ((size_t)bh * NN + q0 + l15) * 32 + quad * 8);

    float eqn_q[4], hqn_q[4], cq[4];
    #pragma unroll
    for (int r = 0; r < 4; ++r) {
        const int t = q0 + quad * 4 + r;
        eqn_q[r] = eqn[(size_t)bh * NN + t];
        hqn_q[r] = hqn[(size_t)bh * NN + t];
        cq[r] = 1.0f - hqn_q[r];
    }

    floatx4 oacc[4];
    #pragma unroll
    for (int db = 0; db < 4; ++db) oacc[db] = (floatx4){0.f, 0.f, 0.f, 0.f};
    float mrun[4], lrun[4];
    #pragma unroll
    for (int r = 0; r < 4; ++r) { mrun[r] = -INFINITY; lrun[r] = 0.f; }

    for (int kt = 0; kt < NN / 32; ++kt) {
        float lg[2][4];
        #pragma unroll
        for (int sub = 0; sub < 2; ++sub) {
            const int m0 = kt * 32 + sub * 16;
            short8 Eb[2], Sb[2], Hb;
            #pragma unroll
            for (int c = 0; c < 2; ++c) {
                Eb[c] = *(const short8*)(ek + ((size_t)bh * NN + m0 + l15) * 64 + c * 32 + quad * 8);
                Sb[c] = *(const short8*)(sk + ((size_t)bh * NN + m0 + l15) * 64 + c * 32 + quad * 8);
            }
            Hb = *(const short8*)(hk + ((size_t)bh * NN + m0 + l15) * 32 + quad * 8);

            floatx4 z = (floatx4){0.f, 0.f, 0.f, 0.f};
            floatx4 se = mfma16(Ea[1], Eb[1], mfma16(Ea[0], Eb[0], z));
            floatx4 ss = mfma16(Sa[1], Sb[1], mfma16(Sa[0], Sb[0], z));
            floatx4 sh = mfma16(Ha, Hb, z);

            const int m = m0 + l15;
            const float ekn_m = ekn[(size_t)bh * NN + m];
            const float hkn_m = hkn[(size_t)bh * NN + m];
            const float ck = 1.0f - hkn_m;
            #pragma unroll
            for (int r = 0; r < 4; ++r) {
                const float dE = sqrtf(fmaxf(eqn_q[r] + ekn_m - 2.f * se[r], 1e-12f));
                const float sim = fminf(fmaxf(ss[r], -0.999999f), 0.999999f);
                const float dS = acosf(sim);
                const float dns = fmaxf(hqn_q[r] + hkn_m - 2.f * sh[r], 0.f);
                const float arg = fmaxf(1.f + 2.f * dns / (cq[r] * ck + 1e-8f), 1.f + 1e-6f);
                const float dH = acoshf(arg);
                lg[sub][r] = -(spA * dE + spB * dS + spG * dH) * invT;
            }
        }
        // online softmax update (per q-row r; rescale ONLY component r of oacc)
        #pragma unroll
        for (int r = 0; r < 4; ++r) {
            const float tmax = qmax16(fmaxf(lg[0][r], lg[1][r]));
            const float newM = fmaxf(mrun[r], tmax);
            const float al = expf(mrun[r] - newM);     // first tile: exp(-inf)=0
            const float p0 = expf(lg[0][r] - newM);
            const float p1 = expf(lg[1][r] - newM);
            const float ts = qsum16(p0 + p1);
            lrun[r] = lrun[r] * al + ts;
            mrun[r] = newM;
            #pragma unroll
            for (int db = 0; db < 4; ++db) oacc[db][r] = oacc[db][r] * al;
            plds[w][quad * 4 + r][l15] = (u16)f2bf(p0);
            plds[w][quad * 4 + r][16 + l15] = (u16)f2bf(p1);
        }
        // P: C-layout -> A-layout via per-wave LDS (wave-synchronous)
        short8 Pa = *(const short8*)(&plds[w][l15][quad * 8]);
        const u16* vrow = vt + (size_t)bh * 64 * NN + kt * 32 + quad * 8;
        #pragma unroll
        for (int db = 0; db < 4; ++db) {
            short8 Vb = *(const short8*)(vrow + (size_t)(db * 16 + l15) * NN);
            oacc[db] = mfma16(Pa, Vb, oacc[db]);
        }
    }
    // epilogue: normalize and store head-output (bf16)
    float invl[4];
    #pragma unroll
    for (int r = 0; r < 4; ++r) invl[r] = 1.0f / lrun[r];
    #pragma unroll
    for (int db = 0; db < 4; ++db) {
        #pragma unroll
        for (int r = 0; r < 4; ++r) {
            const int t = q0 + quad * 4 + r;
            ao[((size_t)b * NN + t) * INNERD + h * 64 + db * 16 + l15] =
                (u16)f2bf(oacc[db][r] * invl[r]);
        }
    }
}

// ============================================================================
// K4: out = ao @ w_proj^T + b_proj.  M=4096, O=512, K=512. fp32 out.
// ============================================================================
__global__ __launch_bounds__(256) void k4_proj(const u16* __restrict__ ao,
                                               const u16* __restrict__ wp,
                                               const float* __restrict__ bp,
                                               float* __restrict__ out) {
    const int tm = blockIdx.x * 64;
    const int o0 = blockIdx.y * 64;
    const int lane = threadIdx.x & 63, w = threadIdx.x >> 6;
    const int l15 = lane & 15, quad = lane >> 4;
    const int arow = tm + w * 16 + l15;

    floatx4 acc[4];
    #pragma unroll
    for (int s = 0; s < 4; ++s) acc[s] = (floatx4){0.f, 0.f, 0.f, 0.f};

    for (int kc = 0; kc < INNERD / 32; ++kc) {
        const int k0 = kc * 32 + quad * 8;
        short8 a = *(const short8*)(ao + (size_t)arow * INNERD + k0);
        #pragma unroll
        for (int s = 0; s < 4; ++s) {
            short8 b = *(const short8*)(wp + (size_t)(o0 + s * 16 + l15) * INNERD + k0);
            acc[s] = mfma16(a, b, acc[s]);
        }
    }
    #pragma unroll
    for (int s = 0; s < 4; ++s) {
        const int o = o0 + s * 16 + l15;
        const float bias = bp[o];
        #pragma unroll
        for (int r = 0; r < 4; ++r) {
            const int tok = tm + w * 16 + quad * 4 + r;
            out[(size_t)tok * CC + o] = acc[s][r] + bias;
        }
    }
}

extern "C" void kernel_launch(void* const* d_in, const int* in_sizes, int n_in,
                              void* d_out, int out_size, void* d_ws, size_t ws_size,
                              hipStream_t stream) {
    const float* x     = (const float*)d_in[0];
    const float* wqkv  = (const float*)d_in[1];
    const float* wproj = (const float*)d_in[2];
    const float* bproj = (const float*)d_in[3];
    const float* we    = (const float*)d_in[4];
    const float* be    = (const float*)d_in[5];
    const float* wsp   = (const float*)d_in[6];
    const float* bsp   = (const float*)d_in[7];
    const float* whp   = (const float*)d_in[8];
    const float* bhp   = (const float*)d_in[9];
    const float* pA    = (const float*)d_in[10];
    const float* pB    = (const float*)d_in[11];
    const float* pG    = (const float*)d_in[12];
    const float* pT    = (const float*)d_in[13];

    char* ws = (char*)d_ws;
    u16* xb  = (u16*)(ws + OFF_XB);
    u16* wqb = (u16*)(ws + OFF_WQB);
    u16* wpb = (u16*)(ws + OFF_WPB);
    u16* web = (u16*)(ws + OFF_WEB);
    u16* wsb = (u16*)(ws + OFF_WSB);
    u16* whb = (u16*)(ws + OFF_WHB);
    u16* qkv = (u16*)(ws + OFF_QKV);
    u16* eq = (u16*)(ws + OFF_EQ);
    u16* ek = (u16*)(ws + OFF_EK);
    u16* sq = (u16*)(ws + OFF_SQ);
    u16* sk = (u16*)(ws + OFF_SK);
    u16* hq = (u16*)(ws + OFF_HQ);
    u16* hk = (u16*)(ws + OFF_HK);
    u16* vt = (u16*)(ws + OFF_VT);
    float* eqn = (float*)(ws + OFF_EQN);
    float* ekn = (float*)(ws + OFF_EKN);
    float* hqn = (float*)(ws + OFF_HQN);
    float* hkn = (float*)(ws + OFF_HKN);
    u16* ao = (u16*)(ws + OFF_AO);

    k0_cvt<<<3082, 256, 0, stream>>>(x, wqkv, wproj, we, wsp, whp,
                                     xb, wqb, wpb, web, wsb, whb);
    k1_qkv<<<dim3(MTOK / 64, 1536 / 64), 256, 0, stream>>>(xb, wqb, qkv);
    k2_embed<<<dim3(BHCNT, NN / 64), 256, 0, stream>>>(
        qkv, web, be, wsb, bsp, whb, bhp,
        eq, ek, sq, sk, hq, hk, eqn, ekn, hqn, hkn, vt);
    k3_attn<<<dim3(BHCNT, NN / 64), 256, 0, stream>>>(
        eq, ek, sq, sk, hq, hk, eqn, ekn, hqn, hkn, vt, ao, pA, pB, pG, pT);
    k4_proj<<<dim3(MTOK / 64, CC / 64), 256, 0, stream>>>(ao, wpb, bproj, (float*)d_out);
}

// Round 4
// 289.985 us; speedup vs baseline: 1.5805x; 1.5805x over previous
//
#include <hip/hip_runtime.h>
#include <math.h>

typedef unsigned short u16;
typedef __attribute__((ext_vector_type(8))) short short8;
typedef __attribute__((ext_vector_type(4))) short short4v;
typedef __attribute__((ext_vector_type(4))) float floatx4;

#define BB 4
#define NN 1024
#define CC 512
#define HH 8
#define INNERD 512
#define BHCNT 32
#define MTOK 4096

// ---- workspace layout (bytes) ----
constexpr size_t OFF_XB  = 0;                          // bf16 [4096][512]   = 4194304
constexpr size_t OFF_WQB = 4194304;                    // bf16 [1536][512]   = 1572864
constexpr size_t OFF_WPB = 5767168;                    // bf16 [512][512]    = 524288
constexpr size_t OFF_WEB = 6291456;                    // bf16 [64][64]      = 8192
constexpr size_t OFF_WSB = 6299648;                    // bf16 [64][64]      = 8192
constexpr size_t OFF_WHB = 6307840;                    // bf16 [32][64]      = 4096
constexpr size_t OFF_QKV = 6311936;                    // bf16 [3][B][H][N][64] = 12582912
constexpr size_t OFF_EQ  = 18894848;                   // bf16 [BH][N][64]   = 4194304
constexpr size_t OFF_EK  = 23089152;
constexpr size_t OFF_SQ  = 27283456;
constexpr size_t OFF_SK  = 31477760;
constexpr size_t OFF_HQ  = 35672064;                   // bf16 [BH][N][32]   = 2097152
constexpr size_t OFF_HK  = 37769216;
constexpr size_t OFF_VT  = 39866368;                   // bf16 [BH][64][N]   = 4194304
constexpr size_t OFF_EQN = 44060672;                   // fp32 [BH][N]       = 131072
constexpr size_t OFF_EKN = 44191744;
constexpr size_t OFF_HQN = 44322816;
constexpr size_t OFF_HKN = 44453888;
constexpr size_t OFF_AO  = 44584960;                   // bf16 [B][N][512]   = 4194304

// ---- fast native transcendentals (compile-safe fallbacks) ----
#if __has_builtin(__builtin_amdgcn_exp2f)
#define FEXP2(x) __builtin_amdgcn_exp2f(x)
#else
#define FEXP2(x) exp2f(x)
#endif
#if __has_builtin(__builtin_amdgcn_logf)
#define FLOG2(x) __builtin_amdgcn_logf(x)
#else
#define FLOG2(x) log2f(x)
#endif
#if __has_builtin(__builtin_amdgcn_sqrtf)
#define FSQRT(x) __builtin_amdgcn_sqrtf(x)
#else
#define FSQRT(x) sqrtf(x)
#endif
#if __has_builtin(__builtin_amdgcn_rcpf)
#define FRCP(x) __builtin_amdgcn_rcpf(x)
#else
#define FRCP(x) (1.0f / (x))
#endif

__device__ __forceinline__ short f2bf(float f) {
    unsigned u = __float_as_uint(f);
    unsigned r = u + 0x7fffu + ((u >> 16) & 1u);
    return (short)(r >> 16);
}
__device__ __forceinline__ floatx4 mfma16(short8 a, short8 b, floatx4 c) {
    return __builtin_amdgcn_mfma_f32_16x16x32_bf16(a, b, c, 0, 0, 0);
}
__device__ __forceinline__ float softplusf(float x) { return log1pf(expf(x)); }
__device__ __forceinline__ float qsum16(float v) {
    v += __shfl_xor(v, 1); v += __shfl_xor(v, 2);
    v += __shfl_xor(v, 4); v += __shfl_xor(v, 8);
    return v;
}

// acos via A&S 4.4.45: |err| <= 2e-8 absolute. input pre-clamped to |x|<=0.999999
__device__ __forceinline__ float facos(float x) {
    const float t = fabsf(x);
    float p = -0.0012624911f;
    p = fmaf(p, t, 0.0066700901f);
    p = fmaf(p, t, -0.0170881256f);
    p = fmaf(p, t, 0.0308918810f);
    p = fmaf(p, t, -0.0501743046f);
    p = fmaf(p, t, 0.0889789874f);
    p = fmaf(p, t, -0.2145988016f);
    p = fmaf(p, t, 1.5707963050f);
    const float r = FSQRT(1.0f - t) * p;
    return x >= 0.0f ? r : 3.14159265358979f - r;
}
// acosh(x) = ln(x + sqrt(x^2-1)), x >= 1+1e-6
__device__ __forceinline__ float facosh(float x) {
    const float s = FSQRT(fmaf(x, x, -1.0f));
    return FLOG2(x + s) * 0.6931471805599453f;
}

// ============================================================================
// K0: fp32 -> bf16 conversion of x / w_qkv / w_proj / w_e / w_s / w_h.
// ============================================================================
__global__ __launch_bounds__(256) void k0_cvt(
    const float* __restrict__ x, const float* __restrict__ wq,
    const float* __restrict__ wp, const float* __restrict__ we,
    const float* __restrict__ wsp, const float* __restrict__ whp,
    u16* __restrict__ xb, u16* __restrict__ wqb, u16* __restrict__ wpb,
    u16* __restrict__ web, u16* __restrict__ wsb, u16* __restrict__ whb) {
    const size_t i = ((size_t)blockIdx.x * 256 + threadIdx.x) * 4;
    const float* s; u16* d; size_t off;
    if (i < 2097152)      { s = x;   d = xb;  off = i; }
    else if (i < 2883584) { s = wq;  d = wqb; off = i - 2097152; }
    else if (i < 3145728) { s = wp;  d = wpb; off = i - 2883584; }
    else if (i < 3149824) { s = we;  d = web; off = i - 3145728; }
    else if (i < 3153920) { s = wsp; d = wsb; off = i - 3149824; }
    else                  { s = whp; d = whb; off = i - 3153920; }
    const float4 v = *(const float4*)(s + off);
    short4v o;
    o[0] = f2bf(v.x); o[1] = f2bf(v.y); o[2] = f2bf(v.z); o[3] = f2bf(v.w);
    *(short4v*)(d + off) = o;
}

// ============================================================================
// K1: qkv = x @ w_qkv^T.  M=4096, O=1536, K=512. bf16 out as qkv[s][b][h][n][d].
// ============================================================================
__global__ __launch_bounds__(256) void k1_qkv(const u16* __restrict__ x,
                                              const u16* __restrict__ wqkv,
                                              u16* __restrict__ qkv) {
    const int tm = blockIdx.x * 64;
    const int o0 = blockIdx.y * 64;
    const int lane = threadIdx.x & 63, w = threadIdx.x >> 6;
    const int l15 = lane & 15, quad = lane >> 4;
    const int arow = tm + w * 16 + l15;

    floatx4 acc[4];
    #pragma unroll
    for (int s = 0; s < 4; ++s) acc[s] = (floatx4){0.f, 0.f, 0.f, 0.f};

    for (int kc = 0; kc < CC / 32; ++kc) {
        const int k0 = kc * 32 + quad * 8;
        short8 a = *(const short8*)(x + (size_t)arow * CC + k0);
        #pragma unroll
        for (int s = 0; s < 4; ++s) {
            short8 b = *(const short8*)(wqkv + (size_t)(o0 + s * 16 + l15) * CC + k0);
            acc[s] = mfma16(a, b, acc[s]);
        }
    }
    #pragma unroll
    for (int s = 0; s < 4; ++s) {
        const int o = o0 + s * 16 + l15;
        const int sq_i = o >> 9, rem = o & 511;
        const int h = rem >> 6, d = rem & 63;
        #pragma unroll
        for (int r = 0; r < 4; ++r) {
            const int tok = tm + w * 16 + quad * 4 + r;
            const int bb = tok >> 10, n = tok & (NN - 1);
            qkv[((((size_t)sq_i * BB + bb) * HH + h) * NN + n) * 64 + d] = (u16)f2bf(acc[s][r]);
        }
    }
}

// ============================================================================
// K2: per-token embeddings (MFMA, K=64) + norms + V transpose.
// ============================================================================
__global__ __launch_bounds__(256) void k2_embed(
    const u16* __restrict__ qkv,
    const u16* __restrict__ we, const float* __restrict__ be,
    const u16* __restrict__ wsp, const float* __restrict__ bsp,
    const u16* __restrict__ whp, const float* __restrict__ bhp,
    u16* __restrict__ eq, u16* __restrict__ ek,
    u16* __restrict__ sq, u16* __restrict__ sk,
    u16* __restrict__ hq, u16* __restrict__ hk,
    float* __restrict__ eqn, float* __restrict__ ekn,
    float* __restrict__ hqn, float* __restrict__ hkn,
    u16* __restrict__ vt) {
    const int bh = blockIdx.x, n0 = blockIdx.y * 64;
    const int b = bh >> 3, h = bh & 7;
    const int tid = threadIdx.x, lane = tid & 63, w = tid >> 6;
    const int l15 = lane & 15, quad = lane >> 4;

    for (int src = 0; src < 2; ++src) {
        const u16* qbase = qkv + (((size_t)src * BB + b) * HH + h) * NN * 64;
        const int tokA = n0 + w * 16 + l15;
        short8 afr[2];
        #pragma unroll
        for (int c = 0; c < 2; ++c)
            afr[c] = *(const short8*)(qbase + (size_t)tokA * 64 + c * 32 + quad * 8);

        floatx4 ce[4], cs[4], ch[2];
        #pragma unroll
        for (int i = 0; i < 4; ++i) { ce[i] = (floatx4){0.f,0.f,0.f,0.f}; cs[i] = (floatx4){0.f,0.f,0.f,0.f}; }
        #pragma unroll
        for (int i = 0; i < 2; ++i) ch[i] = (floatx4){0.f,0.f,0.f,0.f};

        #pragma unroll
        for (int c = 0; c < 2; ++c) {
            const int k0 = c * 32 + quad * 8;
            #pragma unroll
            for (int i = 0; i < 4; ++i) {
                short8 bf = *(const short8*)(we + (size_t)(i * 16 + l15) * 64 + k0);
                ce[i] = mfma16(afr[c], bf, ce[i]);
            }
            #pragma unroll
            for (int i = 0; i < 4; ++i) {
                short8 bf = *(const short8*)(wsp + (size_t)(i * 16 + l15) * 64 + k0);
                cs[i] = mfma16(afr[c], bf, cs[i]);
            }
            #pragma unroll
            for (int i = 0; i < 2; ++i) {
                short8 bf = *(const short8*)(whp + (size_t)(i * 16 + l15) * 64 + k0);
                ch[i] = mfma16(afr[c], bf, ch[i]);
            }
        }
        u16* edst = src ? ek : eq;
        u16* sdst = src ? sk : sq;
        u16* hdst = src ? hk : hq;
        float* endst = src ? ekn : eqn;
        float* hndst = src ? hkn : hqn;

        // ---- Euclid: bias, round, store, |.|^2 of rounded ----
        float epart[4] = {0.f, 0.f, 0.f, 0.f};
        #pragma unroll
        for (int i = 0; i < 4; ++i) {
            const float bias = be[i * 16 + l15];
            #pragma unroll
            for (int r = 0; r < 4; ++r) {
                const float v = ce[i][r] + bias;
                const short vb = f2bf(v);
                const float vr = __uint_as_float(((unsigned)(u16)vb) << 16);
                epart[r] += vr * vr;
                const int tok = n0 + w * 16 + quad * 4 + r;
                edst[((size_t)bh * NN + tok) * 64 + i * 16 + l15] = (u16)vb;
            }
        }
        #pragma unroll
        for (int r = 0; r < 4; ++r) {
            const float s = qsum16(epart[r]);
            if (l15 == 0) endst[(size_t)bh * NN + n0 + w * 16 + quad * 4 + r] = s;
        }
        // ---- spherical: bias, fp32-normalize, round, store ----
        float sv[4][4], sn2[4] = {0.f, 0.f, 0.f, 0.f};
        #pragma unroll
        for (int i = 0; i < 4; ++i) {
            const float bias = bsp[i * 16 + l15];
            #pragma unroll
            for (int r = 0; r < 4; ++r) {
                const float v = cs[i][r] + bias;
                sv[i][r] = v;
                sn2[r] += v * v;
            }
        }
        float inv[4];
        #pragma unroll
        for (int r = 0; r < 4; ++r) {
            const float t = qsum16(sn2[r]);
            inv[r] = 1.0f / fmaxf(sqrtf(t), 1e-12f);
        }
        #pragma unroll
        for (int i = 0; i < 4; ++i) {
            #pragma unroll
            for (int r = 0; r < 4; ++r) {
                const int tok = n0 + w * 16 + quad * 4 + r;
                sdst[((size_t)bh * NN + tok) * 64 + i * 16 + l15] = (u16)f2bf(sv[i][r] * inv[r]);
            }
        }
        // ---- hyperbolic: tanh, round, store, |.|^2 of rounded ----
        float hpart[4] = {0.f, 0.f, 0.f, 0.f};
        #pragma unroll
        for (int i = 0; i < 2; ++i) {
            const float bias = bhp[i * 16 + l15];
            #pragma unroll
            for (int r = 0; r < 4; ++r) {
                const float v = tanhf(ch[i][r] + bias);
                const short vb = f2bf(v);
                const float vr = __uint_as_float(((unsigned)(u16)vb) << 16);
                hpart[r] += vr * vr;
                const int tok = n0 + w * 16 + quad * 4 + r;
                hdst[((size_t)bh * NN + tok) * 32 + i * 16 + l15] = (u16)vb;
            }
        }
        #pragma unroll
        for (int r = 0; r < 4; ++r) {
            const float s = qsum16(hpart[r]);
            if (l15 == 0) hndst[(size_t)bh * NN + n0 + w * 16 + quad * 4 + r] = s;
        }
    }

    // ---- V transpose 64x64 tile -> vt[bh][d][n] bf16 ----
    __shared__ u16 tile[64][72];
    {
        const u16* vbase = qkv + (((size_t)2 * BB + b) * HH + h) * NN * 64;
        const int row = tid >> 2, c0 = (tid & 3) * 16;
        const u16* p = vbase + (size_t)(n0 + row) * 64 + c0;
        *(short8*)(&tile[row][c0]) = *(const short8*)p;
        *(short8*)(&tile[row][c0 + 8]) = *(const short8*)(p + 8);
    }
    __syncthreads();
    {
        const int d = tid >> 2, nn0 = (tid & 3) * 16;
        short8 o1, o2;
        #pragma unroll
        for (int j = 0; j < 8; ++j) o1[j] = (short)tile[nn0 + j][d];
        #pragma unroll
        for (int j = 0; j < 8; ++j) o2[j] = (short)tile[nn0 + 8 + j][d];
        u16* dst = vt + ((size_t)bh * 64 + d) * NN + n0 + nn0;
        *(short8*)dst = o1;
        *(short8*)(dst + 8) = o2;
    }
}

// ============================================================================
// K3: fused distance-attention. grid (BH, N/64), 256 thr, wave = 16 q-rows.
// Logits <= 0 and bounded below (~ -12) => softmax with FIXED max 0:
// p = exp2(dE*kE + dS*kS + dH*kH) with k* = -softplus(.)*invT*log2e.
// No online max/rescale; per-lane running sum; one qsum16 per row at end.
// ============================================================================
__global__ __launch_bounds__(256) void k3_attn(
    const u16* __restrict__ eq, const u16* __restrict__ ek,
    const u16* __restrict__ sq, const u16* __restrict__ sk,
    const u16* __restrict__ hq, const u16* __restrict__ hk,
    const float* __restrict__ eqn, const float* __restrict__ ekn,
    const float* __restrict__ hqn, const float* __restrict__ hkn,
    const u16* __restrict__ vt, u16* __restrict__ ao,
    const float* __restrict__ pA, const float* __restrict__ pB,
    const float* __restrict__ pG, const float* __restrict__ pT) {
    __shared__ u16 plds[4][16][40];   // pad 32->40 shorts

    const int bh = blockIdx.x, q0b = blockIdx.y * 64;
    const int b = bh >> 3, h = bh & 7;
    const int tid = threadIdx.x, lane = tid & 63, w = tid >> 6;
    const int l15 = lane & 15, quad = lane >> 4;
    const int q0 = q0b + w * 16;

    const float invT = 1.0f / softplusf(pT[0]);
    const float L2E = 1.4426950408889634f;
    const float kE = -softplusf(pA[0]) * invT * L2E;
    const float kS = -softplusf(pB[0]) * invT * L2E;
    const float kH = -softplusf(pG[0]) * invT * L2E;

    // A-operand fragments for this wave's 16 q-rows
    short8 Ea[2], Sa[2], Ha;
    #pragma unroll
    for (int c = 0; c < 2; ++c) {
        Ea[c] = *(const short8*)(eq + ((size_t)bh * NN + q0 + l15) * 64 + c * 32 + quad * 8);
        Sa[c] = *(const short8*)(sq + ((size_t)bh * NN + q0 + l15) * 64 + c * 32 + quad * 8);
    }
    Ha = *(const short8*)(hq + ((size_t)bh * NN + q0 + l15) * 32 + quad * 8);

    float eqn_q[4], hqn_q[4], cq[4];
    #pragma unroll
    for (int r = 0; r < 4; ++r) {
        const int t = q0 + quad * 4 + r;
        eqn_q[r] = eqn[(size_t)bh * NN + t];
        hqn_q[r] = hqn[(size_t)bh * NN + t];
        cq[r] = 1.0f - hqn_q[r];
    }

    floatx4 oacc[4];
    #pragma unroll
    for (int db = 0; db < 4; ++db) oacc[db] = (floatx4){0.f, 0.f, 0.f, 0.f};
    float lsum[4] = {0.f, 0.f, 0.f, 0.f};

    for (int kt = 0; kt < NN / 32; ++kt) {
        #pragma unroll
        for (int sub = 0; sub < 2; ++sub) {
            const int m0 = kt * 32 + sub * 16;
            short8 Eb[2], Sb[2], Hb;
            #pragma unroll
            for (int c = 0; c < 2; ++c) {
                Eb[c] = *(const short8*)(ek + ((size_t)bh * NN + m0 + l15) * 64 + c * 32 + quad * 8);
                Sb[c] = *(const short8*)(sk + ((size_t)bh * NN + m0 + l15) * 64 + c * 32 + quad * 8);
            }
            Hb = *(const short8*)(hk + ((size_t)bh * NN + m0 + l15) * 32 + quad * 8);

            floatx4 z = (floatx4){0.f, 0.f, 0.f, 0.f};
            floatx4 se = mfma16(Ea[1], Eb[1], mfma16(Ea[0], Eb[0], z));
            floatx4 ss = mfma16(Sa[1], Sb[1], mfma16(Sa[0], Sb[0], z));
            floatx4 sh = mfma16(Ha, Hb, z);

            const int m = m0 + l15;
            const float ekn_m = ekn[(size_t)bh * NN + m];
            const float hkn_m = hkn[(size_t)bh * NN + m];
            const float ck = 1.0f - hkn_m;
            #pragma unroll
            for (int r = 0; r < 4; ++r) {
                const float dE = FSQRT(fmaxf(eqn_q[r] + ekn_m - 2.f * se[r], 1e-12f));
                const float sim = fminf(fmaxf(ss[r], -0.999999f), 0.999999f);
                const float dS = facos(sim);
                const float dns = fmaxf(hqn_q[r] + hkn_m - 2.f * sh[r], 0.f);
                const float arg = fmaxf(fmaf(2.f * dns, FRCP(cq[r] * ck + 1e-8f), 1.f), 1.f + 1e-6f);
                const float dH = facosh(arg);
                const float lg2 = fmaf(dE, kE, fmaf(dS, kS, dH * kH));
                const float p = FEXP2(lg2);
                lsum[r] += p;
                plds[w][quad * 4 + r][sub * 16 + l15] = (u16)f2bf(p);
            }
        }
        // P: C-layout -> A-layout via per-wave LDS (wave-synchronous)
        short8 Pa = *(const short8*)(&plds[w][l15][quad * 8]);
        const u16* vrow = vt + (size_t)bh * 64 * NN + kt * 32 + quad * 8;
        #pragma unroll
        for (int db = 0; db < 4; ++db) {
            short8 Vb = *(const short8*)(vrow + (size_t)(db * 16 + l15) * NN);
            oacc[db] = mfma16(Pa, Vb, oacc[db]);
        }
    }
    // epilogue: normalize and store head-output (bf16)
    float invl[4];
    #pragma unroll
    for (int r = 0; r < 4; ++r) invl[r] = FRCP(qsum16(lsum[r]));
    #pragma unroll
    for (int db = 0; db < 4; ++db) {
        #pragma unroll
        for (int r = 0; r < 4; ++r) {
            const int t = q0 + quad * 4 + r;
            ao[((size_t)b * NN + t) * INNERD + h * 64 + db * 16 + l15] =
                (u16)f2bf(oacc[db][r] * invl[r]);
        }
    }
}

// ============================================================================
// K4: out = ao @ w_proj^T + b_proj.  M=4096, O=512, K=512. fp32 out.
// ============================================================================
__global__ __launch_bounds__(256) void k4_proj(const u16* __restrict__ ao,
                                               const u16* __restrict__ wp,
                                               const float* __restrict__ bp,
                                               float* __restrict__ out) {
    const int tm = blockIdx.x * 64;
    const int o0 = blockIdx.y * 64;
    const int lane = threadIdx.x & 63, w = threadIdx.x >> 6;
    const int l15 = lane & 15, quad = lane >> 4;
    const int arow = tm + w * 16 + l15;

    floatx4 acc[4];
    #pragma unroll
    for (int s = 0; s < 4; ++s) acc[s] = (floatx4){0.f, 0.f, 0.f, 0.f};

    for (int kc = 0; kc < INNERD / 32; ++kc) {
        const int k0 = kc * 32 + quad * 8;
        short8 a = *(const short8*)(ao + (size_t)arow * INNERD + k0);
        #pragma unroll
        for (int s = 0; s < 4; ++s) {
            short8 b = *(const short8*)(wp + (size_t)(o0 + s * 16 + l15) * INNERD + k0);
            acc[s] = mfma16(a, b, acc[s]);
        }
    }
    #pragma unroll
    for (int s = 0; s < 4; ++s) {
        const int o = o0 + s * 16 + l15;
        const float bias = bp[o];
        #pragma unroll
        for (int r = 0; r < 4; ++r) {
            const int tok = tm + w * 16 + quad * 4 + r;
            out[(size_t)tok * CC + o] = acc[s][r] + bias;
        }
    }
}

extern "C" void kernel_launch(void* const* d_in, const int* in_sizes, int n_in,
                              void* d_out, int out_size, void* d_ws, size_t ws_size,
                              hipStream_t stream) {
    const float* x     = (const float*)d_in[0];
    const float* wqkv  = (const float*)d_in[1];
    const float* wproj = (const float*)d_in[2];
    const float* bproj = (const float*)d_in[3];
    const float* we    = (const float*)d_in[4];
    const float* be    = (const float*)d_in[5];
    const float* wsp   = (const float*)d_in[6];
    const float* bsp   = (const float*)d_in[7];
    const float* whp   = (const float*)d_in[8];
    const float* bhp   = (const float*)d_in[9];
    const float* pA    = (const float*)d_in[10];
    const float* pB    = (const float*)d_in[11];
    const float* pG    = (const float*)d_in[12];
    const float* pT    = (const float*)d_in[13];

    char* ws = (char*)d_ws;
    u16* xb  = (u16*)(ws + OFF_XB);
    u16* wqb = (u16*)(ws + OFF_WQB);
    u16* wpb = (u16*)(ws + OFF_WPB);
    u16* web = (u16*)(ws + OFF_WEB);
    u16* wsb = (u16*)(ws + OFF_WSB);
    u16* whb = (u16*)(ws + OFF_WHB);
    u16* qkv = (u16*)(ws + OFF_QKV);
    u16* eq = (u16*)(ws + OFF_EQ);
    u16* ek = (u16*)(ws + OFF_EK);
    u16* sq = (u16*)(ws + OFF_SQ);
    u16* sk = (u16*)(ws + OFF_SK);
    u16* hq = (u16*)(ws + OFF_HQ);
    u16* hk = (u16*)(ws + OFF_HK);
    u16* vt = (u16*)(ws + OFF_VT);
    float* eqn = (float*)(ws + OFF_EQN);
    float* ekn = (float*)(ws + OFF_EKN);
    float* hqn = (float*)(ws + OFF_HQN);
    float* hkn = (float*)(ws + OFF_HKN);
    u16* ao = (u16*)(ws + OFF_AO);

    k0_cvt<<<3082, 256, 0, stream>>>(x, wqkv, wproj, we, wsp, whp,
                                     xb, wqb, wpb, web, wsb, whb);
    k1_qkv<<<dim3(MTOK / 64, 1536 / 64), 256, 0, stream>>>(xb, wqb, qkv);
    k2_embed<<<dim3(BHCNT, NN / 64), 256, 0, stream>>>(
        qkv, web, be, wsb, bsp, whb, bhp,
        eq, ek, sq, sk, hq, hk, eqn, ekn, hqn, hkn, vt);
    k3_attn<<<dim3(BHCNT, NN / 64), 256, 0, stream>>>(
        eq, ek, sq, sk, hq, hk, eqn, ekn, hqn, hkn, vt, ao, pA, pB, pG, pT);
    k4_proj<<<dim3(MTOK / 64, CC / 64), 256, 0, stream>>>(ao, wpb, bproj, (float*)d_out);
}